// Round 1
// baseline (183.974 us; speedup 1.0000x reference)
//
#include <hip/hip_runtime.h>
#include <math.h>

#define SQRT3F 1.7320508075688772f

typedef _Float16 half8 __attribute__((ext_vector_type(8)));
typedef _Float16 half4 __attribute__((ext_vector_type(4)));
typedef float    f32x4 __attribute__((ext_vector_type(4)));

// ---------------------------------------------------------------------------
// Round-N: two-kernel structure.
//
// Prepass (once, ~6 MB traffic): f32 -> (hi,lo) f16 split + row squared
// norms into d_ws. Previously this conversion ran 32x per X element / 64x
// per Z element (once per output tile) inside the barrier-serialized main
// kernel.
//
// Main kernel: NO LDS, NO barrier. X (2 MB) and Z (1 MB) preconverted
// arrays are L2-resident; each wave loads its MFMA fragments directly from
// global (16 B/lane, 64 B segments), 48 MFMAs, epilogue, nontemporal
// stores (output is write-once -> keep it out of L2 so X/Z stay cached).
// ~100 VGPR, 0 LDS -> 16 waves/CU, each wave with 12 independent loads in
// flight and no sync points.
// ---------------------------------------------------------------------------

__global__ __launch_bounds__(256)
void matern_prep_kernel(const float* __restrict__ X, const float* __restrict__ Z,
                        _Float16* __restrict__ Xh, _Float16* __restrict__ Xl,
                        _Float16* __restrict__ Zh, _Float16* __restrict__ Zl,
                        float* __restrict__ x2, float* __restrict__ z2,
                        int N, int M) {
    int f = blockIdx.x * 256 + threadIdx.x;   // one float4 (4 elems) per thread
    const int totX = N * 16;                  // float4 chunks in X (D=64 -> 16/row)
    const int tot  = (N + M) * 16;
    if (f >= tot) return;
    const float* src; _Float16 *dh, *dl; float* nrm;
    if (f < totX) { src = X; dh = Xh; dl = Xl; nrm = x2; }
    else          { f -= totX; src = Z; dh = Zh; dl = Zl; nrm = z2; }

    float4 v = *(const float4*)(src + (size_t)f * 4);
    _Float16 hx = (_Float16)v.x, hy = (_Float16)v.y, hz = (_Float16)v.z, hw = (_Float16)v.w;
    half4 hv = { hx, hy, hz, hw };
    half4 lv = { (_Float16)(v.x - (float)hx), (_Float16)(v.y - (float)hy),
                 (_Float16)(v.z - (float)hz), (_Float16)(v.w - (float)hw) };
    *(half4*)(dh + (size_t)f * 4) = hv;
    *(half4*)(dl + (size_t)f * 4) = lv;

    // 16 consecutive threads cover one row (64 floats) -> 16-lane reduce.
    float ssq = v.x * v.x + v.y * v.y + v.z * v.z + v.w * v.w;
    ssq += __shfl_xor(ssq, 1, 16);
    ssq += __shfl_xor(ssq, 2, 16);
    ssq += __shfl_xor(ssq, 4, 16);
    ssq += __shfl_xor(ssq, 8, 16);
    if ((threadIdx.x & 15) == 0) nrm[f >> 4] = ssq;
}

__global__ __launch_bounds__(256, 4)
void matern_main_kernel(const _Float16* __restrict__ Xh, const _Float16* __restrict__ Xl,
                        const _Float16* __restrict__ Zh, const _Float16* __restrict__ Zl,
                        const float* __restrict__ x2, const float* __restrict__ z2,
                        const float* __restrict__ sigma, const float* __restrict__ lengthscale,
                        float* __restrict__ out, int M) {
    const int t    = threadIdx.x;
    const int lane = t & 63;
    const int w    = t >> 6;         // 0..3 waves
    const int wr   = w >> 1;         // 0..1
    const int wc   = w & 1;          // 0..1
    const int m0   = blockIdx.y * 128 + wr * 64;   // X rows owned by this wave
    const int n0   = blockIdx.x * 64  + wc * 32;   // Z rows (output cols)
    const int lm   = lane & 15;
    const int q    = lane >> 4;

    f32x4 acc[4][2];
    #pragma unroll
    for (int a = 0; a < 4; ++a)
        #pragma unroll
        for (int b = 0; b < 2; ++b)
            acc[a][b] = (f32x4){0.f, 0.f, 0.f, 0.f};

    #pragma unroll
    for (int kc = 0; kc < 2; ++kc) {
        const int k = kc * 32 + q * 8;
        half8 ah[4], al[4], bh[2], bl[2];
        #pragma unroll
        for (int mt = 0; mt < 4; ++mt) {
            const int off = (m0 + mt * 16 + lm) * 64 + k;   // halves; 16B aligned
            ah[mt] = *(const half8*)(Xh + off);
            al[mt] = *(const half8*)(Xl + off);
        }
        #pragma unroll
        for (int nt = 0; nt < 2; ++nt) {
            const int off = (n0 + nt * 16 + lm) * 64 + k;
            bh[nt] = *(const half8*)(Zh + off);
            bl[nt] = *(const half8*)(Zl + off);
        }
        #pragma unroll
        for (int mt = 0; mt < 4; ++mt)
            #pragma unroll
            for (int nt = 0; nt < 2; ++nt) {
                acc[mt][nt] = __builtin_amdgcn_mfma_f32_16x16x32_f16(ah[mt], bh[nt], acc[mt][nt], 0, 0, 0);
                acc[mt][nt] = __builtin_amdgcn_mfma_f32_16x16x32_f16(ah[mt], bl[nt], acc[mt][nt], 0, 0, 0);
                acc[mt][nt] = __builtin_amdgcn_mfma_f32_16x16x32_f16(al[mt], bh[nt], acc[mt][nt], 0, 0, 0);
            }
    }

    const float s   = sigma[0];
    const float l   = lengthscale[0];
    const float fac = SQRT3F / l;
    const float s2  = s * s;

    #pragma unroll
    for (int mt = 0; mt < 4; ++mt) {
        const int row0 = m0 + mt * 16 + q * 4;          // multiple of 4 -> f32x4 aligned
        const f32x4 xr = *(const f32x4*)(x2 + row0);
        #pragma unroll
        for (int nt = 0; nt < 2; ++nt) {
            const int col = n0 + nt * 16 + lm;
            const float zc = z2[col];
            float* op = out + (size_t)row0 * (size_t)M + col;
            #pragma unroll
            for (int r = 0; r < 4; ++r) {
                float sq  = xr[r] + zc - 2.0f * acc[mt][nt][r];
                float d   = __builtin_amdgcn_sqrtf(fmaxf(sq, 1e-12f));
                float val = fac * d;
                __builtin_nontemporal_store(s2 * (1.0f + val) * __expf(-val), op);
                op += M;
            }
        }
    }
}

extern "C" void kernel_launch(void* const* d_in, const int* in_sizes, int n_in,
                              void* d_out, int out_size, void* d_ws, size_t ws_size,
                              hipStream_t stream) {
    (void)n_in; (void)out_size; (void)ws_size;
    const float* X   = (const float*)d_in[0];
    const float* Z   = (const float*)d_in[1];
    const float* sig = (const float*)d_in[2];
    const float* len = (const float*)d_in[3];
    float* out = (float*)d_out;

    const int D = 64;
    const int N = in_sizes[0] / D;   // 8192
    const int M = in_sizes[1] / D;   // 4096

    // Workspace layout (256B-aligned slices; total ~3.1 MB).
    char* ws = (char*)d_ws;
    size_t o = 0;
    auto take = [&](size_t bytes) { char* p = ws + o; o += (bytes + 255) & ~(size_t)255; return p; };
    _Float16* Xh = (_Float16*)take((size_t)N * D * sizeof(_Float16));
    _Float16* Xl = (_Float16*)take((size_t)N * D * sizeof(_Float16));
    _Float16* Zh = (_Float16*)take((size_t)M * D * sizeof(_Float16));
    _Float16* Zl = (_Float16*)take((size_t)M * D * sizeof(_Float16));
    float*    x2 = (float*)take((size_t)N * sizeof(float));
    float*    z2 = (float*)take((size_t)M * sizeof(float));

    const int tot = (N + M) * 16;
    matern_prep_kernel<<<(tot + 255) / 256, 256, 0, stream>>>(X, Z, Xh, Xl, Zh, Zl, x2, z2, N, M);

    dim3 grid(M / 64, N / 128);      // 64 x 64 = 4096 blocks, 4 waves each
    matern_main_kernel<<<grid, 256, 0, stream>>>(Xh, Xl, Zh, Zl, x2, z2, sig, len, out, M);
}

// Round 2
// 150.970 us; speedup vs baseline: 1.2186x; 1.2186x over previous
//
#include <hip/hip_runtime.h>
#include <math.h>

#define SQRT3F 1.7320508075688772f

typedef _Float16 half8 __attribute__((ext_vector_type(8)));
typedef _Float16 half4 __attribute__((ext_vector_type(4)));
typedef float    f32x4 __attribute__((ext_vector_type(4)));

// ---------------------------------------------------------------------------
// Round-2: fragment-ordered prepass + barrier-free main kernel.
//
// Prepass: f32 -> (hi,lo) f16 split, written in MFMA FRAGMENT ORDER:
//   cell (R = 16-row block, kc = K-half) holds 64 lanes x 8 halves (1 KB);
//   lane (q=lane>>4, lm=lane&15) owns row R*16+lm, k = kc*32+q*8 .. +8.
// So every main-kernel operand load is ONE contiguous 1 KB wave
// transaction (lane i reads base + i*16B) instead of round-1's 16-way
// 64 B gather. Row norms computed in the same prepass (separate index
// range, 16-lane shfl reduce). Conversion+norms run ONCE per element
// (round-0 redid them 32-64x inside every output tile).
//
// Main kernel: no LDS, no __syncthreads. Operands (~3 MB) are L2/L3
// resident. 48 MFMAs per wave, fused Matern epilogue, regular stores
// (NT stores dropped: suspect in round-1 regression; fills hit 6.3 TB/s
// with regular stores).
// ---------------------------------------------------------------------------

__global__ __launch_bounds__(256)
void matern_prep_kernel(const float* __restrict__ X, const float* __restrict__ Z,
                        _Float16* __restrict__ Xh, _Float16* __restrict__ Xl,
                        _Float16* __restrict__ Zh, _Float16* __restrict__ Zl,
                        float* __restrict__ x2, float* __restrict__ z2,
                        int N, int M) {
    const int idx    = blockIdx.x * 256 + threadIdx.x;
    const int cellsX = N * 8;            // (N/16 rowblocks) * 128 cells
    const int cells  = (N + M) * 8;      // one cell = 8 halves (16 B) per array

    if (idx < cells) {
        // ---- fragment-order conversion: one 16B hi + 16B lo cell ----
        const float* src; _Float16 *dh, *dl; int c = idx;
        if (c < cellsX) { src = X; dh = Xh; dl = Xl; }
        else            { c -= cellsX; src = Z; dh = Zh; dl = Zl; }
        const int R   = c >> 7;          // 16-row block
        const int w_  = c & 127;
        const int kc  = w_ >> 6;         // K half (0..1)
        const int q   = (w_ >> 4) & 3;   // k quarter within half
        const int lm  = w_ & 15;         // row within block
        const int row = R * 16 + lm;
        const int k   = kc * 32 + q * 8;
        const float* p = src + (size_t)row * 64 + k;
        const float4 a = *(const float4*)p;
        const float4 b = *(const float4*)(p + 4);
        const float in[8] = { a.x, a.y, a.z, a.w, b.x, b.y, b.z, b.w };
        half8 hv, lv;
        #pragma unroll
        for (int j = 0; j < 8; ++j) {
            _Float16 h = (_Float16)in[j];
            hv[j] = h;
            lv[j] = (_Float16)(in[j] - (float)h);
        }
        *(half8*)(dh + (size_t)c * 8) = hv;
        *(half8*)(dl + (size_t)c * 8) = lv;
    } else {
        // ---- row squared norms: 16 consecutive threads per row ----
        int f = idx - cells;             // float4-chunk index
        const int totX = N * 16;
        const int tot  = (N + M) * 16;
        if (f >= tot) return;
        const float* src; float* nrm;
        if (f < totX) { src = X; nrm = x2; }
        else          { f -= totX; src = Z; nrm = z2; }
        const float4 v = *(const float4*)(src + (size_t)f * 4);
        float ssq = v.x * v.x + v.y * v.y + v.z * v.z + v.w * v.w;
        ssq += __shfl_xor(ssq, 1, 16);
        ssq += __shfl_xor(ssq, 2, 16);
        ssq += __shfl_xor(ssq, 4, 16);
        ssq += __shfl_xor(ssq, 8, 16);
        if ((threadIdx.x & 15) == 0) nrm[f >> 4] = ssq;
    }
}

__global__ __launch_bounds__(256, 4)
void matern_main_kernel(const _Float16* __restrict__ Xh, const _Float16* __restrict__ Xl,
                        const _Float16* __restrict__ Zh, const _Float16* __restrict__ Zl,
                        const float* __restrict__ x2, const float* __restrict__ z2,
                        const float* __restrict__ sigma, const float* __restrict__ lengthscale,
                        float* __restrict__ out, int M) {
    const int t    = threadIdx.x;
    const int lane = t & 63;
    const int w    = t >> 6;         // 0..3 waves
    const int wr   = w >> 1;         // 0..1
    const int wc   = w & 1;          // 0..1
    const int m0   = blockIdx.y * 128 + wr * 64;   // X rows owned by this wave
    const int n0   = blockIdx.x * 64  + wc * 32;   // Z rows (output cols)
    const int Rb0  = (blockIdx.y * 8) + wr * 4;    // X 16-row-block base
    const int Cb0  = (blockIdx.x * 4) + wc * 2;    // Z 16-row-block base
    const int lm   = lane & 15;
    const int q    = lane >> 4;

    f32x4 acc[4][2];
    #pragma unroll
    for (int a = 0; a < 4; ++a)
        #pragma unroll
        for (int b = 0; b < 2; ++b)
            acc[a][b] = (f32x4){0.f, 0.f, 0.f, 0.f};

    #pragma unroll
    for (int kc = 0; kc < 2; ++kc) {
        half8 ah[4], al[4], bh[2], bl[2];
        #pragma unroll
        for (int mt = 0; mt < 4; ++mt) {
            // one contiguous 1 KB wave load: lane reads base + lane*16B
            const size_t off = ((size_t)(Rb0 + mt) * 2 + kc) * 512 + (size_t)lane * 8;
            ah[mt] = *(const half8*)(Xh + off);
            al[mt] = *(const half8*)(Xl + off);
        }
        #pragma unroll
        for (int nt = 0; nt < 2; ++nt) {
            const size_t off = ((size_t)(Cb0 + nt) * 2 + kc) * 512 + (size_t)lane * 8;
            bh[nt] = *(const half8*)(Zh + off);
            bl[nt] = *(const half8*)(Zl + off);
        }
        #pragma unroll
        for (int mt = 0; mt < 4; ++mt)
            #pragma unroll
            for (int nt = 0; nt < 2; ++nt) {
                acc[mt][nt] = __builtin_amdgcn_mfma_f32_16x16x32_f16(ah[mt], bh[nt], acc[mt][nt], 0, 0, 0);
                acc[mt][nt] = __builtin_amdgcn_mfma_f32_16x16x32_f16(ah[mt], bl[nt], acc[mt][nt], 0, 0, 0);
                acc[mt][nt] = __builtin_amdgcn_mfma_f32_16x16x32_f16(al[mt], bh[nt], acc[mt][nt], 0, 0, 0);
            }
    }

    const float s   = sigma[0];
    const float l   = lengthscale[0];
    const float fac = SQRT3F / l;
    const float s2  = s * s;

    #pragma unroll
    for (int mt = 0; mt < 4; ++mt) {
        const int row0 = m0 + mt * 16 + q * 4;          // multiple of 4 -> f32x4 aligned
        const f32x4 xr = *(const f32x4*)(x2 + row0);
        #pragma unroll
        for (int nt = 0; nt < 2; ++nt) {
            const int col = n0 + nt * 16 + lm;
            const float zc = z2[col];
            float* op = out + (size_t)row0 * (size_t)M + col;
            #pragma unroll
            for (int r = 0; r < 4; ++r) {
                float sq  = xr[r] + zc - 2.0f * acc[mt][nt][r];
                float d   = __builtin_amdgcn_sqrtf(fmaxf(sq, 1e-12f));
                float val = fac * d;
                *op = s2 * (1.0f + val) * __expf(-val);
                op += M;
            }
        }
    }
}

extern "C" void kernel_launch(void* const* d_in, const int* in_sizes, int n_in,
                              void* d_out, int out_size, void* d_ws, size_t ws_size,
                              hipStream_t stream) {
    (void)n_in; (void)out_size; (void)ws_size;
    const float* X   = (const float*)d_in[0];
    const float* Z   = (const float*)d_in[1];
    const float* sig = (const float*)d_in[2];
    const float* len = (const float*)d_in[3];
    float* out = (float*)d_out;

    const int D = 64;
    const int N = in_sizes[0] / D;   // 8192
    const int M = in_sizes[1] / D;   // 4096

    // Workspace layout (256B-aligned slices; total ~3.1 MB).
    char* ws = (char*)d_ws;
    size_t o = 0;
    auto take = [&](size_t bytes) { char* p = ws + o; o += (bytes + 255) & ~(size_t)255; return p; };
    _Float16* Xh = (_Float16*)take((size_t)N * D * sizeof(_Float16));
    _Float16* Xl = (_Float16*)take((size_t)N * D * sizeof(_Float16));
    _Float16* Zh = (_Float16*)take((size_t)M * D * sizeof(_Float16));
    _Float16* Zl = (_Float16*)take((size_t)M * D * sizeof(_Float16));
    float*    x2 = (float*)take((size_t)N * sizeof(float));
    float*    z2 = (float*)take((size_t)M * sizeof(float));

    // prep grid covers fragment cells + norm chunks
    const int cells = (N + M) * 8;
    const int tot   = cells + (N + M) * 16;
    matern_prep_kernel<<<(tot + 255) / 256, 256, 0, stream>>>(X, Z, Xh, Xl, Zh, Zl, x2, z2, N, M);

    dim3 grid(M / 64, N / 128);      // 64 x 64 = 4096 blocks, 4 waves each
    matern_main_kernel<<<grid, 256, 0, stream>>>(Xh, Xl, Zh, Zl, x2, z2, sig, len, out, M);
}